// Round 11
// baseline (422.180 us; speedup 1.0000x reference)
//
#include <hip/hip_runtime.h>

// B=2,H=16,S=2048,D=64 attention, no 1/sqrt(d) scale, fp32 in/out.
// Round 17: R13 exact + fused last-arrival combine.
//  - R16 verdict: prep/PRE staging dead permanently — write-inflation
//    (208MB) reproduced even XCD-aligned; mechanism unresolved. Reverted.
//  - Combine fused into attn: after writing its partial, each block does
//    __threadfence() + atomicAdd(cnt[tile]); the last of the SN split
//    blocks combines the partials and writes O (overlaps other tiles'
//    attn work; attn's memory pipe was 81% idle). cnt zeroed via
//    hipMemsetAsync (graph-capture-legal).
//  - Separate combine_kernel kept only for fallback tiers.
// Carries from R13: PV fused into np loop (Pbs 8KB row-paired, LDS 24KB),
// 3-way key split (grid 1536 = 6 blocks/CU), (256,4), 32-row waves x 4,
// S^T QK, fp16 QK / bf16 PV, XOR swizzles, R9 coalesced staging maps,
// reg-prefetch pipeline, XCD head grouping, exp2/log2e, f32 lp, setprio.

typedef __bf16    bf16_t;
typedef _Float16  f16_t;
typedef __bf16    bf16x8 __attribute__((ext_vector_type(8)));
typedef _Float16  f16x8  __attribute__((ext_vector_type(8)));
typedef float     f32x4  __attribute__((ext_vector_type(4)));

constexpr int S  = 2048;
constexpr int Dh = 64;
constexpr int KT = 64;
constexpr int QT = 128;
constexpr float LOG2E = 1.44269504088896340736f;

// XOR swizzle on rows of 64 elems (2B each): 16B chunk idx ^= (row&7).
__device__ __forceinline__ int sw(int row, int col) {
    return row * 64 + ((((col >> 3) ^ (row & 7)) << 3) | (col & 7));
}

// P buffer swizzle: rows paired into 64 x 64-elem rows (128B, full 32 banks),
// then the same 16B-chunk XOR. row in [0,128), k in [0,32).
__device__ __forceinline__ int swp(int row, int k) {
    return sw(row >> 1, (row & 1) * 32 + k);
}

template<int SN, bool FUSE>
__global__ __launch_bounds__(256, 4)
void attn_kernel(const float* __restrict__ Qg,
                 const float* __restrict__ Kg,
                 const float* __restrict__ Vg,
                 float* __restrict__ Og,
                 float* __restrict__ Opart,
                 float* __restrict__ lpart,
                 int*   __restrict__ cnt)
{
    __shared__ alignas(16) f16_t  Khs[KT * Dh];   // K   [key][d]  fp16 (8 KB)
    __shared__ alignas(16) bf16_t Vts[Dh * KT];   // V^T [d][key]  bf16 (8 KB)
    __shared__ alignas(16) bf16_t Pbs[64 * 64];   // P   row-paired (8 KB)

    const int tid  = threadIdx.x;
    const int lane = tid & 63;
    const int wv   = tid >> 6;       // wave 0..3
    const int l15  = lane & 15;
    const int qd   = lane >> 4;      // quad 0..3
    const int wb   = wv * 32;        // wave's 32-row base in the 128-row tile

    const int bx   = blockIdx.x;
    const int head = bx & 31;                    // XCD grouping
    const int r5   = bx >> 5;
    const int qt   = r5 / SN;                    // 0..15
    const int half = r5 % SN;
    const int tile = head * 16 + qt;             // flat output tile id
    const int ch0  = (SN == 3) ? half * 11 : half * 16;
    const int nch  = (SN == 3) ? (half == 2 ? 10 : 11) : (SN == 2 ? 16 : 32);

    const float* Qp = Qg + (size_t)tile * QT * Dh;
    const float* Kp = Kg + (size_t)head * S * Dh;
    const float* Vp = Vg + (size_t)head * S * Dh;

    // staging address components (constant per thread) — R9 map (coalesced)
    const int skey = tid >> 4;          // K staging: key row
    const int sc4  = (tid & 15) * 4;    // K staging: 4-elem col
    const int vkb  = (tid >> 4) * 4;    // V staging: 4 consecutive keys
    const int vc4  = (tid & 15) * 4;    // V staging: 4 consecutive d

    // ---- Q fragments (B-frag), 2 subtiles x 2 k-steps; log2(e) folded ----
    f16x8 qf[2][2];
    #pragma unroll
    for (int sub = 0; sub < 2; ++sub) {
        const float* qrow = Qp + (size_t)(wb + sub * 16 + l15) * Dh;
        #pragma unroll
        for (int ks = 0; ks < 2; ++ks) {
            const float* p = qrow + ks * 32 + qd * 8;
            const float4 a = *(const float4*)(p);
            const float4 b = *(const float4*)(p + 4);
            const float xs[8] = {a.x, a.y, a.z, a.w, b.x, b.y, b.z, b.w};
            #pragma unroll
            for (int j = 0; j < 8; ++j) qf[sub][ks][j] = (f16_t)(xs[j] * LOG2E);
        }
    }

    f32x4 oa[2][4];      // O acc: [subtile][4 d-tiles of 16]
    float lp[2];         // row-sum partial per subtile (lane's q-row = l15)
    #pragma unroll
    for (int s2 = 0; s2 < 2; ++s2) {
        lp[s2] = 0.f;
        #pragma unroll
        for (int t = 0; t < 4; ++t) oa[s2][t] = (f32x4){0.f, 0.f, 0.f, 0.f};
    }

    // ---- prefetch first chunk into registers ----
    float4 kbuf[4], vbuf[4];
    {
        const float* Kc = Kp + (size_t)ch0 * KT * Dh;
        const float* Vc = Vp + (size_t)ch0 * KT * Dh;
        #pragma unroll
        for (int it = 0; it < 4; ++it)
            kbuf[it] = *(const float4*)(Kc + (size_t)(it * 16 + skey) * Dh + sc4);
        #pragma unroll
        for (int i = 0; i < 4; ++i)
            vbuf[i] = *(const float4*)(Vc + (size_t)(vkb + i) * Dh + vc4);
    }

    #pragma unroll 1
    for (int ci = 0; ci < nch; ++ci) {
        __syncthreads();   // prior iter done reading Khs/Vts

        // ---- write staged registers -> LDS (cvt off the load path) ----
        #pragma unroll
        for (int it = 0; it < 4; ++it) {
            const float xs[4] = {kbuf[it].x, kbuf[it].y, kbuf[it].z, kbuf[it].w};
            union { f16_t h[4]; uint2 u; } ph;
            #pragma unroll
            for (int j = 0; j < 4; ++j) ph.h[j] = (f16_t)xs[j];
            *(uint2*)&Khs[sw(it * 16 + skey, sc4)] = ph.u;
        }
        {
            const float rs[4][4] = {{vbuf[0].x, vbuf[1].x, vbuf[2].x, vbuf[3].x},
                                    {vbuf[0].y, vbuf[1].y, vbuf[2].y, vbuf[3].y},
                                    {vbuf[0].z, vbuf[1].z, vbuf[2].z, vbuf[3].z},
                                    {vbuf[0].w, vbuf[1].w, vbuf[2].w, vbuf[3].w}};
            #pragma unroll
            for (int i = 0; i < 4; ++i) {
                union { bf16_t h[4]; uint2 u; } pv;
                #pragma unroll
                for (int j = 0; j < 4; ++j) pv.h[j] = (bf16_t)rs[i][j];
                *(uint2*)&Vts[sw(vc4 + i, vkb)] = pv.u;
            }
        }
        __syncthreads();

        // ---- issue global loads for next chunk (consumed next iteration) ----
        if (ci + 1 < nch) {
            const float* Kc = Kp + (size_t)(ch0 + ci + 1) * KT * Dh;
            const float* Vc = Vp + (size_t)(ch0 + ci + 1) * KT * Dh;
            #pragma unroll
            for (int it = 0; it < 4; ++it)
                kbuf[it] = *(const float4*)(Kc + (size_t)(it * 16 + skey) * Dh + sc4);
            #pragma unroll
            for (int i = 0; i < 4; ++i)
                vbuf[i] = *(const float4*)(Vc + (size_t)(vkb + i) * Dh + vc4);
        }

        // ---- fused per-np: QK (32 keys) -> exp/P -> PV(ks=np) ----
        #pragma unroll
        for (int np = 0; np < 2; ++np) {
            f32x4 st[2][2];   // [sub][nt within pair]
            #pragma unroll
            for (int s2 = 0; s2 < 2; ++s2)
                #pragma unroll
                for (int t = 0; t < 2; ++t) st[s2][t] = (f32x4){0.f, 0.f, 0.f, 0.f};
            __builtin_amdgcn_s_setprio(1);
            #pragma unroll
            for (int ks = 0; ks < 2; ++ks) {
                const int co = ks * 32 + qd * 8;
                const f16x8 ak0 = *(const f16x8*)&Khs[sw((np * 2 + 0) * 16 + l15, co)];
                const f16x8 ak1 = *(const f16x8*)&Khs[sw((np * 2 + 1) * 16 + l15, co)];
                #pragma unroll
                for (int s2 = 0; s2 < 2; ++s2) {
                    st[s2][0] = __builtin_amdgcn_mfma_f32_16x16x32_f16(ak0, qf[s2][ks], st[s2][0], 0, 0, 0);
                    st[s2][1] = __builtin_amdgcn_mfma_f32_16x16x32_f16(ak1, qf[s2][ks], st[s2][1], 0, 0, 0);
                }
            }
            __builtin_amdgcn_s_setprio(0);
            // p = 2^s; store this np's 32 keys into the 8KB P buffer.
            // Same-wave DS ordering makes the np0-read -> np1-write reuse safe.
            #pragma unroll
            for (int s2 = 0; s2 < 2; ++s2) {
                #pragma unroll
                for (int t = 0; t < 2; ++t) {
                    union { bf16_t h[4]; uint2 u; } pb;
                    #pragma unroll
                    for (int r = 0; r < 4; ++r) {
                        const float e = __builtin_amdgcn_exp2f(st[s2][t][r]);
                        lp[s2] += e;
                        pb.h[r] = (bf16_t)e;
                    }
                    *(uint2*)&Pbs[swp(wb + s2 * 16 + l15, t * 16 + qd * 4)] = pb.u;
                }
            }
            // PV for ks=np (vb shared across subtiles)
            const int co = np * 32 + qd * 8;
            const bf16x8 pa0 = *(const bf16x8*)&Pbs[swp(wb + l15,      qd * 8)];
            const bf16x8 pa1 = *(const bf16x8*)&Pbs[swp(wb + 16 + l15, qd * 8)];
            __builtin_amdgcn_s_setprio(1);
            #pragma unroll
            for (int dt = 0; dt < 4; ++dt) {
                const bf16x8 vb = *(const bf16x8*)&Vts[sw(dt * 16 + l15, co)];
                oa[0][dt] = __builtin_amdgcn_mfma_f32_16x16x32_bf16(pa0, vb, oa[0][dt], 0, 0, 0);
                oa[1][dt] = __builtin_amdgcn_mfma_f32_16x16x32_bf16(pa1, vb, oa[1][dt], 0, 0, 0);
            }
            __builtin_amdgcn_s_setprio(0);
        }
    }

    // ---- reduce row sums (lane's lp covers q-row=l15; reduce across quads) ----
    #pragma unroll
    for (int s2 = 0; s2 < 2; ++s2) {
        lp[s2] += __shfl_xor(lp[s2], 16, 64);
        lp[s2] += __shfl_xor(lp[s2], 32, 64);
    }

    if (SN > 1) {
        float* Po = Opart + (size_t)(tile * SN + half) * (QT * Dh);
        float* lq = lpart + (size_t)(tile * SN + half) * QT;
        #pragma unroll
        for (int s2 = 0; s2 < 2; ++s2) {
            if (qd == 0) lq[wb + s2 * 16 + l15] = lp[s2];
            #pragma unroll
            for (int r = 0; r < 4; ++r) {
                const int row = wb + s2 * 16 + qd * 4 + r;
                #pragma unroll
                for (int dt = 0; dt < 4; ++dt)
                    Po[(size_t)row * Dh + dt * 16 + l15] = oa[s2][dt][r];
            }
        }
        if constexpr (FUSE) {
            // ---- last-arrival combine (device-scope fence + atomic, G16) ----
            __threadfence();                         // release partial writes
            __shared__ int lastarrive;
            if (tid == 0) lastarrive = atomicAdd(&cnt[tile], 1);
            __syncthreads();
            if (lastarrive == SN - 1) {
                __threadfence();                     // acquire others' partials
                __shared__ float linv[QT];
                if (tid < QT) {
                    float l = 0.f;
                    #pragma unroll
                    for (int h2 = 0; h2 < SN; ++h2)
                        l += lpart[(size_t)(tile * SN + h2) * QT + tid];
                    linv[tid] = 1.0f / l;
                }
                __syncthreads();
                float4* Ot = (float4*)(Og + (size_t)tile * (QT * Dh));
                #pragma unroll
                for (int k2 = 0; k2 < (QT * Dh / 4) / 256; ++k2) {   // 8 iters
                    const int i = tid + k2 * 256;
                    float4 acc = {0.f, 0.f, 0.f, 0.f};
                    #pragma unroll
                    for (int h2 = 0; h2 < SN; ++h2) {
                        const float4 a = *((const float4*)(Opart
                            + (size_t)(tile * SN + h2) * (QT * Dh)) + i);
                        acc.x += a.x; acc.y += a.y; acc.z += a.z; acc.w += a.w;
                    }
                    const float iv = linv[i >> 4];
                    acc.x *= iv; acc.y *= iv; acc.z *= iv; acc.w *= iv;
                    Ot[i] = acc;
                }
            }
        }
    } else {
        float* Op = Og + (size_t)tile * QT * Dh;
        #pragma unroll
        for (int s2 = 0; s2 < 2; ++s2) {
            #pragma unroll
            for (int r = 0; r < 4; ++r) {
                const float inv = 1.0f / __shfl(lp[s2], qd * 4 + r, 64);
                const int row = wb + s2 * 16 + qd * 4 + r;
                #pragma unroll
                for (int dt = 0; dt < 4; ++dt)
                    Op[(size_t)row * Dh + dt * 16 + l15] = oa[s2][dt][r] * inv;
            }
        }
    }
}

// O = sum(Oi) / sum(li); fallback combine for non-fused tiers.
template<int SN>
__global__ __launch_bounds__(256)
void combine_kernel(const float* __restrict__ Opart,
                    const float* __restrict__ lpart,
                    float* __restrict__ Og)
{
    const int i  = blockIdx.x * 256 + threadIdx.x;   // float4 index
    const int q  = i >> 11;                          // tile 0..511 (2048 f4/tile)
    const int rw = (i >> 4) & 127;                   // row within tile
    const size_t e = (size_t)(i & 2047) * 4;
    float4 acc = {0.f, 0.f, 0.f, 0.f};
    float  l   = 0.f;
    #pragma unroll
    for (int h = 0; h < SN; ++h) {
        const float4 a = *(const float4*)(Opart + (size_t)(q * SN + h) * (QT * Dh) + e);
        l += lpart[(size_t)(q * SN + h) * QT + rw];
        acc.x += a.x; acc.y += a.y; acc.z += a.z; acc.w += a.w;
    }
    const float inv = 1.0f / l;
    float4 o;
    o.x = acc.x * inv; o.y = acc.y * inv; o.z = acc.z * inv; o.w = acc.w * inv;
    *(float4*)(Og + (size_t)i * 4) = o;
}

extern "C" void kernel_launch(void* const* d_in, const int* in_sizes, int n_in,
                              void* d_out, int out_size, void* d_ws, size_t ws_size,
                              hipStream_t stream)
{
    const float* Q = (const float*)d_in[0];
    const float* K = (const float*)d_in[1];
    const float* V = (const float*)d_in[2];
    float*       O = (float*)d_out;

    constexpr size_t TILE_O = (size_t)QT * Dh;                 // floats per tile
    constexpr size_t OP3 = 512ull * 3 * TILE_O;
    constexpr size_t LP3 = 512ull * 3 * QT;
    constexpr size_t OP2 = 512ull * 2 * TILE_O;
    constexpr size_t LP2 = 512ull * 2 * QT;
    constexpr size_t CNT_BYTES = 512 * sizeof(int);
    constexpr size_t NEED3 = (OP3 + LP3) * sizeof(float);      // ~51.1MB
    constexpr size_t NEED2 = (OP2 + LP2) * sizeof(float);      // ~34.1MB
    const int n4 = (int)(512 * TILE_O / 4);                    // output float4 count

    if (ws_size >= NEED3 + CNT_BYTES) {
        // tier 1: 3-way split, fused last-arrival combine
        float* Opart = (float*)d_ws;
        float* lpart = Opart + OP3;
        int*   cnt   = (int*)(lpart + LP3);
        hipMemsetAsync(cnt, 0, CNT_BYTES, stream);
        attn_kernel<3, true><<<dim3(1536), dim3(256), 0, stream>>>(
            Q, K, V, O, Opart, lpart, cnt);
    } else if (ws_size >= NEED3) {
        // tier 2: exact R13 (separate combine)
        float* Opart = (float*)d_ws;
        float* lpart = Opart + OP3;
        attn_kernel<3, false><<<dim3(1536), dim3(256), 0, stream>>>(
            Q, K, V, nullptr, Opart, lpart, nullptr);
        combine_kernel<3><<<dim3(n4 / 256), dim3(256), 0, stream>>>(Opart, lpart, O);
    } else if (ws_size >= NEED2 + CNT_BYTES) {
        float* Opart = (float*)d_ws;
        float* lpart = Opart + OP2;
        int*   cnt   = (int*)(lpart + LP2);
        hipMemsetAsync(cnt, 0, CNT_BYTES, stream);
        attn_kernel<2, true><<<dim3(1024), dim3(256), 0, stream>>>(
            Q, K, V, O, Opart, lpart, cnt);
    } else if (ws_size >= NEED2) {
        float* Opart = (float*)d_ws;
        float* lpart = Opart + OP2;
        attn_kernel<2, false><<<dim3(1024), dim3(256), 0, stream>>>(
            Q, K, V, nullptr, Opart, lpart, nullptr);
        combine_kernel<2><<<dim3(n4 / 256), dim3(256), 0, stream>>>(Opart, lpart, O);
    } else {
        attn_kernel<1, false><<<dim3(512), dim3(256), 0, stream>>>(
            Q, K, V, O, nullptr, nullptr, nullptr);
    }
}

// Round 12
// 201.307 us; speedup vs baseline: 2.0972x; 2.0972x over previous
//
#include <hip/hip_runtime.h>

// B=2,H=16,S=2048,D=64 attention, no 1/sqrt(d) scale, fp32 in/out.
// Round 18: R13 + K/V LDS double-buffer -> ONE barrier per iteration.
//  - R17 verdict: fused last-arrival combine dead — __threadfence() on all
//    blocks = per-block L2 writeback, 5x wall with all pipes <6%. Reverted.
//  - R13's per-iter chain was barrier -> LDS-write -> barrier -> compute:
//    staging writes on the critical path. Now: compute buf[cur] -> write
//    buf[cur^1] (regs loaded a full iter ago; vmcnt hidden under compute)
//    -> issue loads for ci+2 -> single barrier. Write/read separation is
//    guaranteed by the one barrier (reads of buf[cur] in iter i end before
//    barrier i; writes to buf[cur] occur in iter i+1 after barrier i).
//  - Cost: LDS 24->40KB => residency 6->4 blocks/CU. Explicit A/B vs R13:
//    betting barrier-halving + staging overlap > residency loss. If attn
//    >=70us, revert to R13 as final.
// Carries from R13: PV fused into np loop (Pbs 8KB row-paired), 3-way key
// split (grid 1536) + combine kernel, (256,4), 32-row waves x 4, S^T QK,
// fp16 QK / bf16 PV, XOR swizzles, R9 coalesced staging maps, XCD head
// grouping, exp2/log2e, f32 lp, setprio.

typedef __bf16    bf16_t;
typedef _Float16  f16_t;
typedef __bf16    bf16x8 __attribute__((ext_vector_type(8)));
typedef _Float16  f16x8  __attribute__((ext_vector_type(8)));
typedef float     f32x4  __attribute__((ext_vector_type(4)));

constexpr int S  = 2048;
constexpr int Dh = 64;
constexpr int KT = 64;
constexpr int QT = 128;
constexpr float LOG2E = 1.44269504088896340736f;

// XOR swizzle on rows of 64 elems (2B each): 16B chunk idx ^= (row&7).
__device__ __forceinline__ int sw(int row, int col) {
    return row * 64 + ((((col >> 3) ^ (row & 7)) << 3) | (col & 7));
}

// P buffer swizzle: rows paired into 64 x 64-elem rows (128B, full 32 banks),
// then the same 16B-chunk XOR. row in [0,128), k in [0,32).
__device__ __forceinline__ int swp(int row, int k) {
    return sw(row >> 1, (row & 1) * 32 + k);
}

template<int SN>
__global__ __launch_bounds__(256, 4)
void attn_kernel(const float* __restrict__ Qg,
                 const float* __restrict__ Kg,
                 const float* __restrict__ Vg,
                 float* __restrict__ Og,
                 float* __restrict__ Opart,
                 float* __restrict__ lpart)
{
    __shared__ alignas(16) f16_t  Khs[2][KT * Dh];   // K  [key][d] fp16 (2x8KB)
    __shared__ alignas(16) bf16_t Vts[2][KT * Dh];   // V^T [d][key] bf16 (2x8KB)
    __shared__ alignas(16) bf16_t Pbs[64 * 64];      // P  row-paired (8KB)

    const int tid  = threadIdx.x;
    const int lane = tid & 63;
    const int wv   = tid >> 6;       // wave 0..3
    const int l15  = lane & 15;
    const int qd   = lane >> 4;      // quad 0..3
    const int wb   = wv * 32;        // wave's 32-row base in the 128-row tile

    const int bx   = blockIdx.x;
    const int head = bx & 31;                    // XCD grouping
    const int r5   = bx >> 5;
    const int qt   = r5 / SN;                    // 0..15
    const int half = r5 % SN;
    const int tile = head * 16 + qt;             // flat output tile id
    const int ch0  = (SN == 3) ? half * 11 : half * 16;
    const int nch  = (SN == 3) ? (half == 2 ? 10 : 11) : (SN == 2 ? 16 : 32);

    const float* Qp = Qg + (size_t)tile * QT * Dh;
    const float* Kp = Kg + (size_t)head * S * Dh;
    const float* Vp = Vg + (size_t)head * S * Dh;

    // staging address components (constant per thread) — R9 map (coalesced)
    const int skey = tid >> 4;          // K staging: key row
    const int sc4  = (tid & 15) * 4;    // K staging: 4-elem col
    const int vkb  = (tid >> 4) * 4;    // V staging: 4 consecutive keys
    const int vc4  = (tid & 15) * 4;    // V staging: 4 consecutive d

    // ---- Q fragments (B-frag), 2 subtiles x 2 k-steps; log2(e) folded ----
    f16x8 qf[2][2];
    #pragma unroll
    for (int sub = 0; sub < 2; ++sub) {
        const float* qrow = Qp + (size_t)(wb + sub * 16 + l15) * Dh;
        #pragma unroll
        for (int ks = 0; ks < 2; ++ks) {
            const float* p = qrow + ks * 32 + qd * 8;
            const float4 a = *(const float4*)(p);
            const float4 b = *(const float4*)(p + 4);
            const float xs[8] = {a.x, a.y, a.z, a.w, b.x, b.y, b.z, b.w};
            #pragma unroll
            for (int j = 0; j < 8; ++j) qf[sub][ks][j] = (f16_t)(xs[j] * LOG2E);
        }
    }

    f32x4 oa[2][4];      // O acc: [subtile][4 d-tiles of 16]
    float lp[2];         // row-sum partial per subtile (lane's q-row = l15)
    #pragma unroll
    for (int s2 = 0; s2 < 2; ++s2) {
        lp[s2] = 0.f;
        #pragma unroll
        for (int t = 0; t < 4; ++t) oa[s2][t] = (f32x4){0.f, 0.f, 0.f, 0.f};
    }

    float4 kbuf[4], vbuf[4];

    // macros-in-spirit: load chunk c into regs / write regs into LDS buf b
    auto LOADCH = [&](int c) {
        const float* Kc = Kp + (size_t)c * KT * Dh;
        const float* Vc = Vp + (size_t)c * KT * Dh;
        #pragma unroll
        for (int it = 0; it < 4; ++it)
            kbuf[it] = *(const float4*)(Kc + (size_t)(it * 16 + skey) * Dh + sc4);
        #pragma unroll
        for (int i = 0; i < 4; ++i)
            vbuf[i] = *(const float4*)(Vc + (size_t)(vkb + i) * Dh + vc4);
    };
    auto WRITEBUF = [&](int b) {
        #pragma unroll
        for (int it = 0; it < 4; ++it) {
            const float xs[4] = {kbuf[it].x, kbuf[it].y, kbuf[it].z, kbuf[it].w};
            union { f16_t h[4]; uint2 u; } ph;
            #pragma unroll
            for (int j = 0; j < 4; ++j) ph.h[j] = (f16_t)xs[j];
            *(uint2*)&Khs[b][sw(it * 16 + skey, sc4)] = ph.u;
        }
        const float rs[4][4] = {{vbuf[0].x, vbuf[1].x, vbuf[2].x, vbuf[3].x},
                                {vbuf[0].y, vbuf[1].y, vbuf[2].y, vbuf[3].y},
                                {vbuf[0].z, vbuf[1].z, vbuf[2].z, vbuf[3].z},
                                {vbuf[0].w, vbuf[1].w, vbuf[2].w, vbuf[3].w}};
        #pragma unroll
        for (int i = 0; i < 4; ++i) {
            union { bf16_t h[4]; uint2 u; } pv;
            #pragma unroll
            for (int j = 0; j < 4; ++j) pv.h[j] = (bf16_t)rs[i][j];
            *(uint2*)&Vts[b][sw(vc4 + i, vkb)] = pv.u;
        }
    };

    // ---- prologue: chunk0 -> buf0; issue loads for chunk1 ----
    LOADCH(ch0);
    WRITEBUF(0);
    if (nch > 1) LOADCH(ch0 + 1);
    __syncthreads();   // buf0 ready

    #pragma unroll 1
    for (int ci = 0; ci < nch; ++ci) {
        const int cur = ci & 1;

        // ---- fused per-np: QK (32 keys) -> exp/P -> PV(ks=np) on buf[cur] ----
        #pragma unroll
        for (int np = 0; np < 2; ++np) {
            f32x4 st[2][2];   // [sub][nt within pair]
            #pragma unroll
            for (int s2 = 0; s2 < 2; ++s2)
                #pragma unroll
                for (int t = 0; t < 2; ++t) st[s2][t] = (f32x4){0.f, 0.f, 0.f, 0.f};
            __builtin_amdgcn_s_setprio(1);
            #pragma unroll
            for (int ks = 0; ks < 2; ++ks) {
                const int co = ks * 32 + qd * 8;
                const f16x8 ak0 = *(const f16x8*)&Khs[cur][sw((np * 2 + 0) * 16 + l15, co)];
                const f16x8 ak1 = *(const f16x8*)&Khs[cur][sw((np * 2 + 1) * 16 + l15, co)];
                #pragma unroll
                for (int s2 = 0; s2 < 2; ++s2) {
                    st[s2][0] = __builtin_amdgcn_mfma_f32_16x16x32_f16(ak0, qf[s2][ks], st[s2][0], 0, 0, 0);
                    st[s2][1] = __builtin_amdgcn_mfma_f32_16x16x32_f16(ak1, qf[s2][ks], st[s2][1], 0, 0, 0);
                }
            }
            __builtin_amdgcn_s_setprio(0);
            // p = 2^s; store this np's 32 keys into the 8KB P buffer.
            // Same-wave DS ordering makes the np0-read -> np1-write reuse safe.
            #pragma unroll
            for (int s2 = 0; s2 < 2; ++s2) {
                #pragma unroll
                for (int t = 0; t < 2; ++t) {
                    union { bf16_t h[4]; uint2 u; } pb;
                    #pragma unroll
                    for (int r = 0; r < 4; ++r) {
                        const float e = __builtin_amdgcn_exp2f(st[s2][t][r]);
                        lp[s2] += e;
                        pb.h[r] = (bf16_t)e;
                    }
                    *(uint2*)&Pbs[swp(wb + s2 * 16 + l15, t * 16 + qd * 4)] = pb.u;
                }
            }
            // PV for ks=np (vb shared across subtiles)
            const int co = np * 32 + qd * 8;
            const bf16x8 pa0 = *(const bf16x8*)&Pbs[swp(wb + l15,      qd * 8)];
            const bf16x8 pa1 = *(const bf16x8*)&Pbs[swp(wb + 16 + l15, qd * 8)];
            __builtin_amdgcn_s_setprio(1);
            #pragma unroll
            for (int dt = 0; dt < 4; ++dt) {
                const bf16x8 vb = *(const bf16x8*)&Vts[cur][sw(dt * 16 + l15, co)];
                oa[0][dt] = __builtin_amdgcn_mfma_f32_16x16x32_bf16(pa0, vb, oa[0][dt], 0, 0, 0);
                oa[1][dt] = __builtin_amdgcn_mfma_f32_16x16x32_bf16(pa1, vb, oa[1][dt], 0, 0, 0);
            }
            __builtin_amdgcn_s_setprio(0);
        }

        // ---- stage next chunk into the alternate buffer; prefetch ci+2 ----
        if (ci + 1 < nch) {
            WRITEBUF(cur ^ 1);                 // regs loaded one iter ago
            if (ci + 2 < nch) LOADCH(ch0 + ci + 2);
            __syncthreads();                   // buf[cur^1] ready; buf[cur] free
        }
    }

    // ---- reduce row sums (lane's lp covers q-row=l15; reduce across quads) ----
    #pragma unroll
    for (int s2 = 0; s2 < 2; ++s2) {
        lp[s2] += __shfl_xor(lp[s2], 16, 64);
        lp[s2] += __shfl_xor(lp[s2], 32, 64);
    }

    if (SN > 1) {
        float* Po = Opart + (size_t)(tile * SN + half) * (QT * Dh);
        float* lq = lpart + (size_t)(tile * SN + half) * QT;
        #pragma unroll
        for (int s2 = 0; s2 < 2; ++s2) {
            if (qd == 0) lq[wb + s2 * 16 + l15] = lp[s2];
            #pragma unroll
            for (int r = 0; r < 4; ++r) {
                const int row = wb + s2 * 16 + qd * 4 + r;
                #pragma unroll
                for (int dt = 0; dt < 4; ++dt)
                    Po[(size_t)row * Dh + dt * 16 + l15] = oa[s2][dt][r];
            }
        }
    } else {
        float* Op = Og + (size_t)tile * QT * Dh;
        #pragma unroll
        for (int s2 = 0; s2 < 2; ++s2) {
            #pragma unroll
            for (int r = 0; r < 4; ++r) {
                const float inv = 1.0f / __shfl(lp[s2], qd * 4 + r, 64);
                const int row = wb + s2 * 16 + qd * 4 + r;
                #pragma unroll
                for (int dt = 0; dt < 4; ++dt)
                    Op[(size_t)row * Dh + dt * 16 + l15] = oa[s2][dt][r] * inv;
            }
        }
    }
}

// O = sum(Oi) / sum(li); one thread per float4 of output.
template<int SN>
__global__ __launch_bounds__(256)
void combine_kernel(const float* __restrict__ Opart,
                    const float* __restrict__ lpart,
                    float* __restrict__ Og)
{
    const int i  = blockIdx.x * 256 + threadIdx.x;   // float4 index
    const int q  = i >> 11;                          // tile 0..511 (2048 f4/tile)
    const int rw = (i >> 4) & 127;                   // row within tile
    const size_t e = (size_t)(i & 2047) * 4;
    float4 acc = {0.f, 0.f, 0.f, 0.f};
    float  l   = 0.f;
    #pragma unroll
    for (int h = 0; h < SN; ++h) {
        const float4 a = *(const float4*)(Opart + (size_t)(q * SN + h) * (QT * Dh) + e);
        l += lpart[(size_t)(q * SN + h) * QT + rw];
        acc.x += a.x; acc.y += a.y; acc.z += a.z; acc.w += a.w;
    }
    const float inv = 1.0f / l;
    float4 o;
    o.x = acc.x * inv; o.y = acc.y * inv; o.z = acc.z * inv; o.w = acc.w * inv;
    *(float4*)(Og + (size_t)i * 4) = o;
}

extern "C" void kernel_launch(void* const* d_in, const int* in_sizes, int n_in,
                              void* d_out, int out_size, void* d_ws, size_t ws_size,
                              hipStream_t stream)
{
    const float* Q = (const float*)d_in[0];
    const float* K = (const float*)d_in[1];
    const float* V = (const float*)d_in[2];
    float*       O = (float*)d_out;

    constexpr size_t TILE_O = (size_t)QT * Dh;                 // floats per tile
    constexpr size_t NEED3  = (512ull * 3 * (TILE_O + QT)) * sizeof(float); // ~51.1MB
    constexpr size_t NEED2  = (512ull * 2 * (TILE_O + QT)) * sizeof(float); // ~34.1MB
    const int n4 = (int)(512 * TILE_O / 4);                    // output float4 count

    if (ws_size >= NEED3) {
        // 3-way key split, double-buffered attn
        float* Opart = (float*)d_ws;
        float* lpart = Opart + 512ull * 3 * TILE_O;
        attn_kernel<3><<<dim3(1536), dim3(256), 0, stream>>>(
            Q, K, V, nullptr, Opart, lpart);
        combine_kernel<3><<<dim3(n4 / 256), dim3(256), 0, stream>>>(Opart, lpart, O);
    } else if (ws_size >= NEED2) {
        float* Opart = (float*)d_ws;
        float* lpart = Opart + 512ull * 2 * TILE_O;
        attn_kernel<2><<<dim3(1024), dim3(256), 0, stream>>>(
            Q, K, V, nullptr, Opart, lpart);
        combine_kernel<2><<<dim3(n4 / 256), dim3(256), 0, stream>>>(Opart, lpart, O);
    } else {
        attn_kernel<1><<<dim3(512), dim3(256), 0, stream>>>(
            Q, K, V, O, nullptr, nullptr);
    }
}

// Round 15
// 142.350 us; speedup vs baseline: 2.9658x; 1.4142x over previous
//
#include <hip/hip_runtime.h>

// B=2,H=16,S=2048,D=64 attention, no 1/sqrt(d) scale, fp32 in/out.
// Round 19, attempt 3 (two consecutive container-acquire infra failures on
// this source, no kernel verdict either time; R6/R7/R8 showed the same
// 2-streak resolving on the identical 3rd submission). R13 exact main loop
// + bf16 O-partials (combine-traffic halving).
//  - R18 verdict: LDS double-buffer dead — restructure spilled to scratch
//    (WRITE 165MB, attn 2x). R13 loop restored byte-identical.
//  - Only the epilogue + combine change: Opart stored as bf16 (lpart stays
//    fp32). Opart write 50->25MB, combine read 100->50MB; combine does 8
//    elems/thread via uint4-of-bf16. Added error ~ 2^-9 * sum|O_h|/l ~
//    0.006 absolute (absmax 0.031 -> ~0.035 expected).
//  - If absmax fails threshold, next round reverts to exact R13 as final.
// Carries from R13: PV fused into np loop (Pbs 8KB row-paired, LDS 24KB),
// 3-way key split (grid 1536 = 6 blocks/CU), (256,4), 32-row waves x 4,
// S^T QK, fp16 QK / bf16 PV, XOR swizzles, R9 coalesced staging maps,
// reg-prefetch pipeline, XCD head grouping, exp2/log2e, f32 lp, setprio.

typedef __bf16    bf16_t;
typedef _Float16  f16_t;
typedef __bf16    bf16x8 __attribute__((ext_vector_type(8)));
typedef _Float16  f16x8  __attribute__((ext_vector_type(8)));
typedef float     f32x4  __attribute__((ext_vector_type(4)));

constexpr int S  = 2048;
constexpr int Dh = 64;
constexpr int KT = 64;
constexpr int QT = 128;
constexpr float LOG2E = 1.44269504088896340736f;

// XOR swizzle on rows of 64 elems (2B each): 16B chunk idx ^= (row&7).
__device__ __forceinline__ int sw(int row, int col) {
    return row * 64 + ((((col >> 3) ^ (row & 7)) << 3) | (col & 7));
}

// P buffer swizzle: rows paired into 64 x 64-elem rows (128B, full 32 banks),
// then the same 16B-chunk XOR. row in [0,128), k in [0,32).
__device__ __forceinline__ int swp(int row, int k) {
    return sw(row >> 1, (row & 1) * 32 + k);
}

template<int SN>
__global__ __launch_bounds__(256, 4)
void attn_kernel(const float* __restrict__ Qg,
                 const float* __restrict__ Kg,
                 const float* __restrict__ Vg,
                 float* __restrict__ Og,
                 bf16_t* __restrict__ Opart,
                 float* __restrict__ lpart)
{
    __shared__ alignas(16) f16_t  Khs[KT * Dh];   // K   [key][d]  fp16 (8 KB)
    __shared__ alignas(16) bf16_t Vts[Dh * KT];   // V^T [d][key]  bf16 (8 KB)
    __shared__ alignas(16) bf16_t Pbs[64 * 64];   // P   row-paired (8 KB)

    const int tid  = threadIdx.x;
    const int lane = tid & 63;
    const int wv   = tid >> 6;       // wave 0..3
    const int l15  = lane & 15;
    const int qd   = lane >> 4;      // quad 0..3
    const int wb   = wv * 32;        // wave's 32-row base in the 128-row tile

    const int bx   = blockIdx.x;
    const int head = bx & 31;                    // XCD grouping
    const int r5   = bx >> 5;
    const int qt   = r5 / SN;                    // 0..15
    const int half = r5 % SN;
    const int tile = head * 16 + qt;             // flat output tile id
    const int ch0  = (SN == 3) ? half * 11 : half * 16;
    const int nch  = (SN == 3) ? (half == 2 ? 10 : 11) : (SN == 2 ? 16 : 32);

    const float* Qp = Qg + (size_t)tile * QT * Dh;
    const float* Kp = Kg + (size_t)head * S * Dh;
    const float* Vp = Vg + (size_t)head * S * Dh;

    // staging address components (constant per thread) — R9 map (coalesced)
    const int skey = tid >> 4;          // K staging: key row
    const int sc4  = (tid & 15) * 4;    // K staging: 4-elem col
    const int vkb  = (tid >> 4) * 4;    // V staging: 4 consecutive keys
    const int vc4  = (tid & 15) * 4;    // V staging: 4 consecutive d

    // ---- Q fragments (B-frag), 2 subtiles x 2 k-steps; log2(e) folded ----
    f16x8 qf[2][2];
    #pragma unroll
    for (int sub = 0; sub < 2; ++sub) {
        const float* qrow = Qp + (size_t)(wb + sub * 16 + l15) * Dh;
        #pragma unroll
        for (int ks = 0; ks < 2; ++ks) {
            const float* p = qrow + ks * 32 + qd * 8;
            const float4 a = *(const float4*)(p);
            const float4 b = *(const float4*)(p + 4);
            const float xs[8] = {a.x, a.y, a.z, a.w, b.x, b.y, b.z, b.w};
            #pragma unroll
            for (int j = 0; j < 8; ++j) qf[sub][ks][j] = (f16_t)(xs[j] * LOG2E);
        }
    }

    f32x4 oa[2][4];      // O acc: [subtile][4 d-tiles of 16]
    float lp[2];         // row-sum partial per subtile (lane's q-row = l15)
    #pragma unroll
    for (int s2 = 0; s2 < 2; ++s2) {
        lp[s2] = 0.f;
        #pragma unroll
        for (int t = 0; t < 4; ++t) oa[s2][t] = (f32x4){0.f, 0.f, 0.f, 0.f};
    }

    // ---- prefetch first chunk into registers ----
    float4 kbuf[4], vbuf[4];
    {
        const float* Kc = Kp + (size_t)ch0 * KT * Dh;
        const float* Vc = Vp + (size_t)ch0 * KT * Dh;
        #pragma unroll
        for (int it = 0; it < 4; ++it)
            kbuf[it] = *(const float4*)(Kc + (size_t)(it * 16 + skey) * Dh + sc4);
        #pragma unroll
        for (int i = 0; i < 4; ++i)
            vbuf[i] = *(const float4*)(Vc + (size_t)(vkb + i) * Dh + vc4);
    }

    #pragma unroll 1
    for (int ci = 0; ci < nch; ++ci) {
        __syncthreads();   // prior iter done reading Khs/Vts

        // ---- write staged registers -> LDS (cvt off the load path) ----
        #pragma unroll
        for (int it = 0; it < 4; ++it) {
            const float xs[4] = {kbuf[it].x, kbuf[it].y, kbuf[it].z, kbuf[it].w};
            union { f16_t h[4]; uint2 u; } ph;
            #pragma unroll
            for (int j = 0; j < 4; ++j) ph.h[j] = (f16_t)xs[j];
            *(uint2*)&Khs[sw(it * 16 + skey, sc4)] = ph.u;
        }
        {
            const float rs[4][4] = {{vbuf[0].x, vbuf[1].x, vbuf[2].x, vbuf[3].x},
                                    {vbuf[0].y, vbuf[1].y, vbuf[2].y, vbuf[3].y},
                                    {vbuf[0].z, vbuf[1].z, vbuf[2].z, vbuf[3].z},
                                    {vbuf[0].w, vbuf[1].w, vbuf[2].w, vbuf[3].w}};
            #pragma unroll
            for (int i = 0; i < 4; ++i) {
                union { bf16_t h[4]; uint2 u; } pv;
                #pragma unroll
                for (int j = 0; j < 4; ++j) pv.h[j] = (bf16_t)rs[i][j];
                *(uint2*)&Vts[sw(vc4 + i, vkb)] = pv.u;
            }
        }
        __syncthreads();

        // ---- issue global loads for next chunk (consumed next iteration) ----
        if (ci + 1 < nch) {
            const float* Kc = Kp + (size_t)(ch0 + ci + 1) * KT * Dh;
            const float* Vc = Vp + (size_t)(ch0 + ci + 1) * KT * Dh;
            #pragma unroll
            for (int it = 0; it < 4; ++it)
                kbuf[it] = *(const float4*)(Kc + (size_t)(it * 16 + skey) * Dh + sc4);
            #pragma unroll
            for (int i = 0; i < 4; ++i)
                vbuf[i] = *(const float4*)(Vc + (size_t)(vkb + i) * Dh + vc4);
        }

        // ---- fused per-np: QK (32 keys) -> exp/P -> PV(ks=np) ----
        #pragma unroll
        for (int np = 0; np < 2; ++np) {
            f32x4 st[2][2];   // [sub][nt within pair]
            #pragma unroll
            for (int s2 = 0; s2 < 2; ++s2)
                #pragma unroll
                for (int t = 0; t < 2; ++t) st[s2][t] = (f32x4){0.f, 0.f, 0.f, 0.f};
            __builtin_amdgcn_s_setprio(1);
            #pragma unroll
            for (int ks = 0; ks < 2; ++ks) {
                const int co = ks * 32 + qd * 8;
                const f16x8 ak0 = *(const f16x8*)&Khs[sw((np * 2 + 0) * 16 + l15, co)];
                const f16x8 ak1 = *(const f16x8*)&Khs[sw((np * 2 + 1) * 16 + l15, co)];
                #pragma unroll
                for (int s2 = 0; s2 < 2; ++s2) {
                    st[s2][0] = __builtin_amdgcn_mfma_f32_16x16x32_f16(ak0, qf[s2][ks], st[s2][0], 0, 0, 0);
                    st[s2][1] = __builtin_amdgcn_mfma_f32_16x16x32_f16(ak1, qf[s2][ks], st[s2][1], 0, 0, 0);
                }
            }
            __builtin_amdgcn_s_setprio(0);
            // p = 2^s; store this np's 32 keys into the 8KB P buffer.
            // Same-wave DS ordering makes the np0-read -> np1-write reuse safe.
            #pragma unroll
            for (int s2 = 0; s2 < 2; ++s2) {
                #pragma unroll
                for (int t = 0; t < 2; ++t) {
                    union { bf16_t h[4]; uint2 u; } pb;
                    #pragma unroll
                    for (int r = 0; r < 4; ++r) {
                        const float e = __builtin_amdgcn_exp2f(st[s2][t][r]);
                        lp[s2] += e;
                        pb.h[r] = (bf16_t)e;
                    }
                    *(uint2*)&Pbs[swp(wb + s2 * 16 + l15, t * 16 + qd * 4)] = pb.u;
                }
            }
            // PV for ks=np (vb shared across subtiles)
            const int co = np * 32 + qd * 8;
            const bf16x8 pa0 = *(const bf16x8*)&Pbs[swp(wb + l15,      qd * 8)];
            const bf16x8 pa1 = *(const bf16x8*)&Pbs[swp(wb + 16 + l15, qd * 8)];
            __builtin_amdgcn_s_setprio(1);
            #pragma unroll
            for (int dt = 0; dt < 4; ++dt) {
                const bf16x8 vb = *(const bf16x8*)&Vts[sw(dt * 16 + l15, co)];
                oa[0][dt] = __builtin_amdgcn_mfma_f32_16x16x32_bf16(pa0, vb, oa[0][dt], 0, 0, 0);
                oa[1][dt] = __builtin_amdgcn_mfma_f32_16x16x32_bf16(pa1, vb, oa[1][dt], 0, 0, 0);
            }
            __builtin_amdgcn_s_setprio(0);
        }
    }

    // ---- reduce row sums (lane's lp covers q-row=l15; reduce across quads) ----
    #pragma unroll
    for (int s2 = 0; s2 < 2; ++s2) {
        lp[s2] += __shfl_xor(lp[s2], 16, 64);
        lp[s2] += __shfl_xor(lp[s2], 32, 64);
    }

    if (SN > 1) {
        bf16_t* Po = Opart + (size_t)(tile * SN + half) * (QT * Dh);
        float*  lq = lpart + (size_t)(tile * SN + half) * QT;
        #pragma unroll
        for (int s2 = 0; s2 < 2; ++s2) {
            if (qd == 0) lq[wb + s2 * 16 + l15] = lp[s2];
            #pragma unroll
            for (int r = 0; r < 4; ++r) {
                const int row = wb + s2 * 16 + qd * 4 + r;
                #pragma unroll
                for (int dt = 0; dt < 4; ++dt)
                    Po[(size_t)row * Dh + dt * 16 + l15] = (bf16_t)oa[s2][dt][r];
            }
        }
    } else {
        float* Op = Og + (size_t)tile * QT * Dh;
        #pragma unroll
        for (int s2 = 0; s2 < 2; ++s2) {
            #pragma unroll
            for (int r = 0; r < 4; ++r) {
                const float inv = 1.0f / __shfl(lp[s2], qd * 4 + r, 64);
                const int row = wb + s2 * 16 + qd * 4 + r;
                #pragma unroll
                for (int dt = 0; dt < 4; ++dt)
                    Op[(size_t)row * Dh + dt * 16 + l15] = oa[s2][dt][r] * inv;
            }
        }
    }
}

// O = sum(Oi) / sum(li); 8 output floats per thread (uint4 of bf16 per partial).
template<int SN>
__global__ __launch_bounds__(256)
void combine_kernel(const bf16_t* __restrict__ Opart,
                    const float* __restrict__ lpart,
                    float* __restrict__ Og)
{
    const int i  = blockIdx.x * 256 + threadIdx.x;   // 8-elem group index
    const int q  = i >> 10;                          // tile (1024 groups/tile)
    const int rw = (i >> 3) & 127;                   // row within tile
    const int e  = (i & 1023) * 8;                   // elem offset within tile
    float l = 0.f;
    float acc[8] = {0.f, 0.f, 0.f, 0.f, 0.f, 0.f, 0.f, 0.f};
    #pragma unroll
    for (int h = 0; h < SN; ++h) {
        l += lpart[(size_t)(q * SN + h) * QT + rw];
        union { uint4 v; unsigned short s[8]; } raw;
        raw.v = *(const uint4*)(Opart + (size_t)(q * SN + h) * (QT * Dh) + e);
        #pragma unroll
        for (int j = 0; j < 8; ++j) {
            union { unsigned short u; bf16_t b; } cv;
            cv.u = raw.s[j];
            acc[j] += (float)cv.b;
        }
    }
    const float inv = 1.0f / l;
    float4 o0, o1;
    o0.x = acc[0] * inv; o0.y = acc[1] * inv; o0.z = acc[2] * inv; o0.w = acc[3] * inv;
    o1.x = acc[4] * inv; o1.y = acc[5] * inv; o1.z = acc[6] * inv; o1.w = acc[7] * inv;
    float* Ot = Og + (size_t)q * (QT * Dh) + e;
    *(float4*)Ot       = o0;
    *(float4*)(Ot + 4) = o1;
}

extern "C" void kernel_launch(void* const* d_in, const int* in_sizes, int n_in,
                              void* d_out, int out_size, void* d_ws, size_t ws_size,
                              hipStream_t stream)
{
    const float* Q = (const float*)d_in[0];
    const float* K = (const float*)d_in[1];
    const float* V = (const float*)d_in[2];
    float*       O = (float*)d_out;

    constexpr size_t TILE_O = (size_t)QT * Dh;                 // elems per tile
    constexpr size_t OPE3 = 512ull * 3 * TILE_O;               // bf16 elems
    constexpr size_t LP3  = 512ull * 3 * QT;                   // fp32 elems
    constexpr size_t OPE2 = 512ull * 2 * TILE_O;
    constexpr size_t LP2  = 512ull * 2 * QT;
    constexpr size_t NEED3 = OPE3 * 2 + LP3 * 4;               // ~26 MB
    constexpr size_t NEED2 = OPE2 * 2 + LP2 * 4;               // ~17 MB
    const int n8 = (int)(512 * TILE_O / 8);                    // 8-elem groups

    if (ws_size >= NEED3) {
        // 3-way key split: grid 1536 = 6 blocks/CU
        bf16_t* Opart = (bf16_t*)d_ws;
        float*  lpart = (float*)(Opart + OPE3);
        attn_kernel<3><<<dim3(1536), dim3(256), 0, stream>>>(
            Q, K, V, nullptr, Opart, lpart);
        combine_kernel<3><<<dim3(n8 / 256), dim3(256), 0, stream>>>(Opart, lpart, O);
    } else if (ws_size >= NEED2) {
        bf16_t* Opart = (bf16_t*)d_ws;
        float*  lpart = (float*)(Opart + OPE2);
        attn_kernel<2><<<dim3(1024), dim3(256), 0, stream>>>(
            Q, K, V, nullptr, Opart, lpart);
        combine_kernel<2><<<dim3(n8 / 256), dim3(256), 0, stream>>>(Opart, lpart, O);
    } else {
        attn_kernel<1><<<dim3(512), dim3(256), 0, stream>>>(
            Q, K, V, O, nullptr, nullptr);
    }
}